// Round 1
// baseline (123.476 us; speedup 1.0000x reference)
//
#include <hip/hip_runtime.h>

// Problem constants (from reference)
constexpr int B_  = 16;
constexpr int A_  = 3;     // MASK_SIZE
constexpr int C_  = 80;    // NUM_CLASSES
constexpr int T_  = 50;    // MAX_BOXES
constexpr int H_  = 76;
constexpr int W_  = 76;
constexpr int HW_ = H_ * W_;                  // 5776
constexpr int BSTR_ = A_ * (5 + C_) * HW_;    // 1472880 (batch stride in elements)
constexpr float NETW_ = 608.0f;
constexpr float NETH_ = 608.0f;

constexpr int NCONF_BLOCKS  = 192;
constexpr int CONF_SLICES   = B_ * A_;        // 48 (b,a) conf planes
constexpr int F4_PER_SLICE  = HW_ / 4;        // 1444 float4 per plane
constexpr int CONF_F4       = CONF_SLICES * F4_PER_SLICE; // 69312

__device__ const float ANCH[18] = {
    10.f, 13.f, 16.f, 30.f, 33.f, 23.f, 30.f, 61.f, 62.f,
    45.f, 59.f, 119.f, 116.f, 90.f, 156.f, 198.f, 373.f, 326.f};

__device__ __forceinline__ float sigf(float z) {
    return 1.0f / (1.0f + expf(-z));
}

__device__ __forceinline__ float waveRed(float v) {
    // full 64-lane wave reduction
    #pragma unroll
    for (int o = 32; o > 0; o >>= 1) v += __shfl_down(v, o);
    return v;
}

// ws layout (floats):
//  [0..15]   lcoord per batch
//  [16..31]  lcls per batch
//  [32..47]  valid count per batch
//  [48..63]  unique assigned-cell count per batch
//  [64..64+NCONF_BLOCKS) conf partial sums
__global__ __launch_bounds__(256) void yolo_main(const float* __restrict__ inp,
                                                 const float* __restrict__ tgt,
                                                 float* __restrict__ ws) {
    const int tid = threadIdx.x;
    const int bid = blockIdx.x;

    if (bid >= B_) {
        // ---------- conf-channel sigmoid sum ----------
        const int cb = bid - B_;
        float s = 0.0f;
        for (int f = cb * 256 + tid; f < CONF_F4; f += NCONF_BLOCKS * 256) {
            const int sl   = f / F4_PER_SLICE;
            const int pos4 = f - sl * F4_PER_SLICE;
            const int b    = sl / A_;
            const int a    = sl - b * A_;
            const float4 v = *reinterpret_cast<const float4*>(
                inp + b * BSTR_ + (a * 85 + 4) * HW_ + pos4 * 4);
            s += sigf(v.x) + sigf(v.y) + sigf(v.z) + sigf(v.w);
        }
        __shared__ float red[4];
        s = waveRed(s);
        if ((tid & 63) == 0) red[tid >> 6] = s;
        __syncthreads();
        if (tid == 0) ws[64 + cb] = red[0] + red[1] + red[2] + red[3];
        return;
    }

    // ---------- per-batch target processing ----------
    const int b = bid;
    __shared__ int sh_cell[T_];   // cell id within batch, -1 if not assigned
    __shared__ int sh_base[T_];   // element index of pred[b, a, :, gj, gi] channel 0
    __shared__ int sh_cls[T_];

    float lcoord = 0.0f, lcls = 0.0f, vcnt = 0.0f, ucnt = 0.0f;

    if (tid < T_) sh_cell[tid] = -1;

    if (tid < T_) {
        const float* tp = tgt + (b * T_ + tid) * 5;
        const float tc = tp[0], tx = tp[1], ty = tp[2], tw = tp[3], th = tp[4];
        const bool valid = (tc + tx + ty + tw + th) != 0.0f;
        vcnt = valid ? 1.0f : 0.0f;

        // best of 9 anchors by zero-centered IoU (first max wins, like argmax)
        float bestv = -1.0f;
        int besti = 0;
        #pragma unroll
        for (int k = 0; k < 9; ++k) {
            const float aw = ANCH[2 * k]     * (1.0f / NETW_);
            const float ah = ANCH[2 * k + 1] * (1.0f / NETH_);
            const float in = fminf(tw, aw) * fminf(th, ah);
            const float un = tw * th + aw * ah - in;
            const float iou = in / un;
            if (iou > bestv) { bestv = iou; besti = k; }
        }

        if (valid && besti < A_) {
            int gi = (int)(tx * (float)W_);
            gi = gi < 0 ? 0 : (gi > W_ - 1 ? W_ - 1 : gi);
            int gj = (int)(ty * (float)H_);
            gj = gj < 0 ? 0 : (gj > H_ - 1 ? H_ - 1 : gj);

            const int cell = (besti * H_ + gj) * W_ + gi;
            const int base = b * BSTR_ + besti * 85 * HW_ + gj * W_ + gi;
            sh_cell[tid] = cell;
            sh_base[tid] = base;
            sh_cls[tid]  = (int)tc;

            const float txt = tx * (float)W_ - (float)gi;
            const float tyt = ty * (float)H_ - (float)gj;
            const float twt = logf(tw * NETW_ / ANCH[2 * besti]);
            const float tht = logf(th * NETH_ / ANCH[2 * besti + 1]);
            const float scale = 2.0f * ty * tw;  // faithful: 2*t[2]*t[3]

            const float px = sigf(inp[base]);
            const float py = sigf(inp[base + HW_]);
            const float pw = inp[base + 2 * HW_];
            const float ph = inp[base + 3 * HW_];
            lcoord = scale * (fabsf(px - txt) + fabsf(py - tyt) +
                              fabsf(pw - twt) + fabsf(ph - tht));
        }
    }
    __syncthreads();

    // unique-cell count (first occurrence within the batch counts)
    if (tid < T_ && sh_cell[tid] >= 0) {
        bool uniq = true;
        for (int q = 0; q < tid; ++q)
            if (sh_cell[q] == sh_cell[tid]) { uniq = false; break; }
        ucnt = uniq ? 1.0f : 0.0f;
    }

    // class BCE: distribute (target, class) pairs over the block
    for (int p = tid; p < T_ * C_; p += 256) {
        const int t = p / C_;
        const int c = p - t * C_;
        if (sh_cell[t] >= 0) {
            const float z  = inp[sh_base[t] + (5 + c) * HW_];
            const float pc = sigf(z);
            const float oh = (c == sh_cls[t]) ? 1.0f : 0.0f;
            lcls -= oh * logf(pc) + (1.0f - oh) * log1pf(-pc);
        }
    }

    // block-reduce the 4 partials and write per-batch slots
    __shared__ float red2[4][4];
    float vals[4] = {lcoord, lcls, vcnt, ucnt};
    #pragma unroll
    for (int k = 0; k < 4; ++k) {
        const float r = waveRed(vals[k]);
        if ((tid & 63) == 0) red2[k][tid >> 6] = r;
    }
    __syncthreads();
    if (tid == 0) {
        ws[b]      = red2[0][0] + red2[0][1] + red2[0][2] + red2[0][3];
        ws[16 + b] = red2[1][0] + red2[1][1] + red2[1][2] + red2[1][3];
        ws[32 + b] = red2[2][0] + red2[2][1] + red2[2][2] + red2[2][3];
        ws[48 + b] = red2[3][0] + red2[3][1] + red2[3][2] + red2[3][3];
    }
}

__global__ __launch_bounds__(256) void yolo_fin(const float* __restrict__ ws,
                                                float* __restrict__ out) {
    const int tid = threadIdx.x;
    float s = 0.0f;
    for (int i = tid; i < NCONF_BLOCKS; i += 256) s += ws[64 + i];
    __shared__ float red[4];
    s = waveRed(s);
    if ((tid & 63) == 0) red[tid >> 6] = s;
    __syncthreads();
    if (tid == 0) {
        const float conf_sum = red[0] + red[1] + red[2] + red[3];
        float lcoord = 0.f, lcls = 0.f, vcnt = 0.f, ucnt = 0.f;
        for (int b = 0; b < B_; ++b) {
            lcoord += ws[b];
            lcls   += ws[16 + b];
            vcnt   += ws[32 + b];
            ucnt   += ws[48 + b];
        }
        const float nt = fmaxf(vcnt, 1.0f);
        out[0] = (conf_sum - ucnt) + lcoord / nt + lcls;
    }
}

extern "C" void kernel_launch(void* const* d_in, const int* in_sizes, int n_in,
                              void* d_out, int out_size, void* d_ws, size_t ws_size,
                              hipStream_t stream) {
    const float* inp = (const float*)d_in[0];
    const float* tgt = (const float*)d_in[1];
    float* ws  = (float*)d_ws;
    float* out = (float*)d_out;

    yolo_main<<<B_ + NCONF_BLOCKS, 256, 0, stream>>>(inp, tgt, ws);
    yolo_fin<<<1, 256, 0, stream>>>(ws, out);
}